// Round 6
// baseline (257.670 us; speedup 1.0000x reference)
//
#include <hip/hip_runtime.h>
#include <stdint.h>

// MLA attention, MI355X round 6.
// Stage 1: kv = compressed_kv @ w_up^T  (bf16 MFMA, m97-style 128x128 tile)
// Stage 2: causal flash attention, 16-wave (1024-thr) swapped-QK^T 32x32x16:
//   wave = (k-quarter 0-3) x (q-strip 0-3); q-tile 128, KV tile 128.
//   4-way k-split online softmax, 2-stage bf16 tree merge at pass end.
//   Kn/Kr via global_load_lds XOR-swizzled dbuf; V reg-prefetch -> packed Vt.
//   Causal balance: block = q-tile pair (7-p, p) = 9 tiles; grid 256 = 1/CU.
//   __launch_bounds__(1024,4): VGPR<=128 so all 16 waves resident (4/SIMD).

#define Hz 16
#define Sz 1024
#define RANKz 512
#define SCALEf 0.07216878364870323f
#define CRr(r) ((((r) & 3)) + 8 * ((r) >> 2) + 4 * hi)

typedef unsigned short u16;
typedef __attribute__((ext_vector_type(8))) short bf16x8;
typedef __attribute__((ext_vector_type(4))) float f32x4;
typedef __attribute__((ext_vector_type(16))) float f32x16;

__device__ __forceinline__ u16 f2b(float f) {
  union { float f; uint32_t u; } x; x.f = f;
  return (u16)((x.u + 0x7fffu + ((x.u >> 16) & 1u)) >> 16);
}
__device__ __forceinline__ float b2f(u16 s) {
  union { uint32_t u; float f; } x; x.u = ((uint32_t)s) << 16;
  return x.f;
}
__device__ __forceinline__ uint32_t cvtpk(float lo, float hi_) {
  uint32_t r;
  asm("v_cvt_pk_bf16_f32 %0, %1, %2" : "=v"(r) : "v"(lo), "v"(hi_));
  return r;
}

// ---------------------------------------------------------------- cvt fp32->bf16
__global__ void cvt_bf16_kernel(const float* __restrict__ a, u16* __restrict__ ao,
                                const float* __restrict__ b, u16* __restrict__ bo,
                                const float* __restrict__ c, u16* __restrict__ co,
                                int na, int nb) {
  int idx = blockIdx.x * blockDim.x + threadIdx.x;
  const float* s; u16* d; int i;
  if (idx < na)            { s = a; d = ao; i = idx; }
  else if (idx < na + nb)  { s = b; d = bo; i = idx - na; }
  else                     { s = c; d = co; i = idx - na - nb; }
  float4 v = ((const float4*)s)[i];
  ushort4 o = make_ushort4(f2b(v.x), f2b(v.y), f2b(v.z), f2b(v.w));
  ((ushort4*)d)[i] = o;
}

// ---------------------------------------------------------------- stage 1 GEMM
__global__ __launch_bounds__(256)
void gemm_kv_bf16(const u16* __restrict__ A,
                  const u16* __restrict__ Bm,
                  u16* __restrict__ C) {
  __shared__ u16 As[128 * 32];
  __shared__ u16 Bs[128 * 32];
  const int tid = threadIdx.x;
  const int w = tid >> 6, lane = tid & 63;
  const int wr = w >> 1, wc = w & 1;
  const int row0 = blockIdx.x * 128, col0 = blockIdx.y * 128;
  f32x4 acc[4][4];
#pragma unroll
  for (int m = 0; m < 4; ++m)
#pragma unroll
    for (int n = 0; n < 4; ++n) acc[m][n] = (f32x4){0.f, 0.f, 0.f, 0.f};

  const int rstage = (lane >> 2);
  const int cstage = (lane & 3) * 8;

  for (int kt = 0; kt < RANKz / 32; ++kt) {
    const int k0 = kt * 32;
#pragma unroll
    for (int i = 0; i < 2; ++i) {
      const int chunk = i * 4 + w;
      const int r = chunk * 16 + rstage;
      const u16* ga = A  + (size_t)(row0 + r) * RANKz + k0 + cstage;
      const u16* gb = Bm + (size_t)(col0 + r) * RANKz + k0 + cstage;
      __builtin_amdgcn_global_load_lds((const __attribute__((address_space(1))) void*)ga,
                                       (__attribute__((address_space(3))) void*)&As[chunk * 512], 16, 0, 0);
      __builtin_amdgcn_global_load_lds((const __attribute__((address_space(1))) void*)gb,
                                       (__attribute__((address_space(3))) void*)&Bs[chunk * 512], 16, 0, 0);
    }
    __syncthreads();
    const int klo = (lane >> 4) * 8;
    bf16x8 af[4], bfr[4];
#pragma unroll
    for (int m = 0; m < 4; ++m)
      af[m] = *(const bf16x8*)&As[(wr * 64 + m * 16 + (lane & 15)) * 32 + klo];
#pragma unroll
    for (int n = 0; n < 4; ++n)
      bfr[n] = *(const bf16x8*)&Bs[(wc * 64 + n * 16 + (lane & 15)) * 32 + klo];
#pragma unroll
    for (int m = 0; m < 4; ++m)
#pragma unroll
      for (int n = 0; n < 4; ++n)
        acc[m][n] = __builtin_amdgcn_mfma_f32_16x16x32_bf16(af[m], bfr[n], acc[m][n], 0, 0, 0);
    __syncthreads();
  }
  const int cb = col0 + wc * 64 + (lane & 15);
  const int rb = row0 + wr * 64 + (lane >> 4) * 4;
#pragma unroll
  for (int m = 0; m < 4; ++m)
#pragma unroll
    for (int n = 0; n < 4; ++n)
#pragma unroll
      for (int j = 0; j < 4; ++j)
        C[(size_t)(rb + m * 16 + j) * 4096 + (cb + n * 16)] = f2b(acc[m][n][j]);
}

// ---------------------------------------------------------------- stage 2: attention
// LDS map: Kn dbuf @0 (2x32K), Kr dbuf @64K (2x16K), Vt @96K (32K). Total 128K.
// Merge reuse: buf0 @0 (32K bf16), buf1 @32K; ml @96K.
__global__ __launch_bounds__(1024, 4)
void mla_attn_mfma(const float* __restrict__ q,
                   const u16* __restrict__ kvb,     // [T][16][256] bf16
                   const u16* __restrict__ ropeb,   // [T][64] bf16
                   float* __restrict__ out) {       // [T][16][128] fp32
  __shared__ __align__(16) unsigned char LB[131072];

  const int tid = threadIdx.x;
  const int w = tid >> 6, lane = tid & 63;
  const int l31 = lane & 31, hi = lane >> 5;
  const int quarter = w >> 2, strip = w & 3;

  const int bid = blockIdx.x;
  const int job = (bid & 7) * 32 + (bid >> 3);   // same-bh jobs -> same XCD
  const int bh = job >> 2, pr = job & 3;
  const int bat = bh >> 4, h = bh & 15;
  const int tok0 = bat * Sz;

  const int vkp = tid & 63, vdc = tid >> 6;      // V stage: k-pair 0-63, d-chunk8 0-15
  uint4 va, vb;                                  // V prefetch regs

  float m_run, l_run;
  f32x16 acc[4];

  auto stageK = [&](int tokt, int buf) {
#pragma unroll
    for (int i = 0; i < 2; ++i) {                // Kn: 32 chunk-groups of 1KB
      const int c = w * 2 + i;
      const int row = c * 4 + (lane >> 4);
      const int sc = (lane & 15) ^ (row & 7);
      const u16* src = kvb + ((size_t)(tokt + row) * Hz + h) * 256 + sc * 8;
      __builtin_amdgcn_global_load_lds((const __attribute__((address_space(1))) void*)src,
                                       (__attribute__((address_space(3))) void*)(LB + buf * 32768 + c * 1024), 16, 0, 0);
    }
    {                                            // Kr: 16 chunk-groups of 1KB
      const int c = w;
      const int row = c * 8 + (lane >> 3);
      const int sc = (lane & 7) ^ (row & 7);
      const u16* src = ropeb + (size_t)(tokt + row) * 64 + sc * 8;
      __builtin_amdgcn_global_load_lds((const __attribute__((address_space(1))) void*)src,
                                       (__attribute__((address_space(3))) void*)(LB + 65536 + buf * 16384 + c * 1024), 16, 0, 0);
    }
  };
  auto loadV = [&](int tokt) {
    const u16* vp = kvb + ((size_t)(tokt + vkp * 2) * Hz + h) * 256 + 128 + vdc * 8;
    va = *(const uint4*)vp;
    vb = *(const uint4*)(vp + 4096);             // next token row (+Hz*256)
  };
  auto writeVt = [&]() {
    union { uint4 v; u16 u[8]; } A_, B_;
    A_.v = va; B_.v = vb;
    uint32_t* vt = (uint32_t*)(LB + 98304);
#pragma unroll
    for (int i = 0; i < 8; ++i) {
      const int d = vdc * 8 + i;
      vt[d * 64 + 4 * ((vkp >> 2) ^ (d & 7)) + (vkp & 3)] =
          (uint32_t)A_.u[i] | ((uint32_t)B_.u[i] << 16);
    }
  };
  auto writePartial = [&](uint32_t* bp, float* mlp) {
    if (hi == 0) {
      mlp[strip * 64 + l31 * 2]     = m_run;
      mlp[strip * 64 + l31 * 2 + 1] = l_run;
    }
#pragma unroll
    for (int db = 0; db < 4; ++db) {
      const int d = db * 32 + l31;
#pragma unroll
      for (int g = 0; g < 4; ++g) {
        uint2 pk;
        pk.x = cvtpk(acc[db][g * 4 + 0], acc[db][g * 4 + 1]);
        pk.y = cvtpk(acc[db][g * 4 + 2], acc[db][g * 4 + 3]);
        *(uint2*)&bp[strip * 2048 + d * 16 + ((g * 4 + 2 * hi) ^ ((d & 7) << 1))] = pk;
      }
    }
  };
  auto mergeIn = [&](const uint32_t* bp, const float* mlp) {
    const float m_p = mlp[strip * 64 + l31 * 2];
    const float l_p = mlp[strip * 64 + l31 * 2 + 1];
    const float M = fmaxf(m_run, m_p);
    const float sA = __expf(m_run - M), sB = __expf(m_p - M);
    l_run = l_run * sA + l_p * sB;
    m_run = M;
    float fa[16], fb[16];
#pragma unroll
    for (int r = 0; r < 16; ++r) { fa[r] = __shfl(sA, CRr(r)); fb[r] = __shfl(sB, CRr(r)); }
#pragma unroll
    for (int db = 0; db < 4; ++db) {
      const int d = db * 32 + l31;
#pragma unroll
      for (int g = 0; g < 4; ++g) {
        uint2 pk = *(const uint2*)&bp[strip * 2048 + d * 16 + ((g * 4 + 2 * hi) ^ ((d & 7) << 1))];
        acc[db][g * 4 + 0] = acc[db][g * 4 + 0] * fa[g * 4 + 0] + b2f((u16)(pk.x & 0xffffu)) * fb[g * 4 + 0];
        acc[db][g * 4 + 1] = acc[db][g * 4 + 1] * fa[g * 4 + 1] + b2f((u16)(pk.x >> 16))     * fb[g * 4 + 1];
        acc[db][g * 4 + 2] = acc[db][g * 4 + 2] * fa[g * 4 + 2] + b2f((u16)(pk.y & 0xffffu)) * fb[g * 4 + 2];
        acc[db][g * 4 + 3] = acc[db][g * 4 + 3] * fa[g * 4 + 3] + b2f((u16)(pk.y >> 16))     * fb[g * 4 + 3];
      }
    }
  };

  uint32_t* buf0 = (uint32_t*)LB;
  uint32_t* buf1 = (uint32_t*)(LB + 32768);
  float* mlA = (float*)(LB + 98304);
  float* mlB = (float*)(LB + 98304 + 1024);

#pragma unroll 1
  for (int pass = 0; pass < 2; ++pass) {
    const int qt = pass ? pr : (7 - pr);
    const int ntiles = qt + 1;
    const int q0 = qt * 128 + strip * 32;       // wave strip's q base (in-batch)

    // ---- Q fragments (B-operand), prescaled by SCALE
    bf16x8 qf[12];
    {
      const float* qp = q + ((size_t)(tok0 + q0 + l31) * Hz + h) * 192 + hi * 8;
#pragma unroll
      for (int ds = 0; ds < 12; ++ds) {
        float4 a = *(const float4*)(qp + ds * 16);
        float4 b = *(const float4*)(qp + ds * 16 + 4);
        union { bf16x8 v; u16 u[8]; } t;
        t.u[0] = f2b(a.x * SCALEf); t.u[1] = f2b(a.y * SCALEf);
        t.u[2] = f2b(a.z * SCALEf); t.u[3] = f2b(a.w * SCALEf);
        t.u[4] = f2b(b.x * SCALEf); t.u[5] = f2b(b.y * SCALEf);
        t.u[6] = f2b(b.z * SCALEf); t.u[7] = f2b(b.w * SCALEf);
        qf[ds] = t.v;
      }
    }

#pragma unroll
    for (int db = 0; db < 4; ++db)
#pragma unroll
      for (int r = 0; r < 16; ++r) acc[db][r] = 0.f;
    m_run = -1e30f; l_run = 0.f;

    // ---- prologue: stage tile 0
    stageK(tok0, 0);
    loadV(tok0);
    __syncthreads();
    writeVt();
    __syncthreads();

#pragma unroll 1
    for (int t = 0; t < ntiles; ++t) {
      const int cur = t & 1;
      const bool havenext = (t + 1 < ntiles);
      if (havenext) {
        stageK(tok0 + (t + 1) * 128, cur ^ 1);
        loadV(tok0 + (t + 1) * 128);
      }

      const bool active = (t * 128 + quarter * 32) <= (q0 + 31);
      if (active) {
        const u16* KnC = (const u16*)(LB + cur * 32768);
        const u16* KrC = (const u16*)(LB + 65536 + cur * 16384);
        const int row_a = quarter * 32 + l31;
        const int swz = row_a & 7;

        f32x16 s0;
#pragma unroll
        for (int r = 0; r < 16; ++r) s0[r] = 0.f;
        __builtin_amdgcn_s_setprio(1);
#pragma unroll
        for (int ds = 0; ds < 8; ++ds) {
          bf16x8 kf = *(const bf16x8*)&KnC[row_a * 128 + 8 * ((2 * ds + hi) ^ swz)];
          s0 = __builtin_amdgcn_mfma_f32_32x32x16_bf16(kf, qf[ds], s0, 0, 0, 0);
        }
#pragma unroll
        for (int ds = 8; ds < 12; ++ds) {
          bf16x8 kf = *(const bf16x8*)&KrC[row_a * 64 + 8 * ((2 * (ds - 8) + hi) ^ swz)];
          s0 = __builtin_amdgcn_mfma_f32_32x32x16_bf16(kf, qf[ds], s0, 0, 0, 0);
        }
        __builtin_amdgcn_s_setprio(0);

        // ---- causal mask (diagonal sub-tile only)
        if (t == qt && quarter == strip) {
#pragma unroll
          for (int r = 0; r < 16; ++r)
            if (CRr(r) > l31) s0[r] = -1e30f;
        }

        // ---- in-register online softmax (lane owns q-col l31), defer-max THR=8
        float mx = s0[0];
#pragma unroll
        for (int r = 1; r < 16; ++r) mx = fmaxf(mx, s0[r]);
        mx = fmaxf(mx, __shfl_xor(mx, 32));
        if (__any(mx > m_run + 8.f)) {
          const float nm = fmaxf(m_run, mx);
          const float cr = __expf(m_run - nm);
          m_run = nm; l_run *= cr;
#pragma unroll
          for (int r = 0; r < 16; ++r) {
            const float crg = __shfl(cr, CRr(r));
#pragma unroll
            for (int db = 0; db < 4; ++db) acc[db][r] *= crg;
          }
        }
        float ts = 0.f;
#pragma unroll
        for (int r = 0; r < 16; ++r) { s0[r] = __expf(s0[r] - m_run); ts += s0[r]; }
        ts += __shfl_xor(ts, 32);
        l_run += ts;

        // ---- P -> A-frags: cvt_pk + xor-32 word swap
        bf16x8 pf[2];
#pragma unroll
        for (int ks = 0; ks < 2; ++ks) {
          const int o = ks * 8;
          const uint32_t w0 = cvtpk(s0[o + 0], s0[o + 1]);
          const uint32_t w1 = cvtpk(s0[o + 4], s0[o + 5]);
          const uint32_t w2 = cvtpk(s0[o + 2], s0[o + 3]);
          const uint32_t w3 = cvtpk(s0[o + 6], s0[o + 7]);
          const uint32_t t0 = __shfl_xor(w0, 32), t1 = __shfl_xor(w1, 32);
          const uint32_t t2 = __shfl_xor(w2, 32), t3 = __shfl_xor(w3, 32);
          union { bf16x8 v; uint32_t u[4]; } P;
          P.u[0] = hi ? t1 : w0;
          P.u[1] = hi ? t3 : w2;
          P.u[2] = hi ? w1 : t0;
          P.u[3] = hi ? w3 : t2;
          pf[ks] = P.v;
        }

        // ---- PV: O[32q x 128d] += P[32q x 32k] * V[32k x 128d]
        const u16* VtC = (const u16*)(LB + 98304);
        __builtin_amdgcn_s_setprio(1);
#pragma unroll
        for (int ks = 0; ks < 2; ++ks)
#pragma unroll
          for (int db = 0; db < 4; ++db) {
            const int d = db * 32 + l31;
            bf16x8 vf = *(const bf16x8*)&VtC[d * 128 + 8 * ((quarter * 4 + 2 * ks + hi) ^ (d & 7))];
            acc[db] = __builtin_amdgcn_mfma_f32_32x32x16_bf16(pf[ks], vf, acc[db], 0, 0, 0);
          }
        __builtin_amdgcn_s_setprio(0);
      }

      __syncthreads();             // A: reads of tile t done; gll(t+1)+V regs drained
      if (havenext) {
        writeVt();
        __syncthreads();           // B: Vt(t+1) published
      }
    }

    // ---- 2-stage bf16 tree merge of the 4 k-quarters, then write out
    if (quarter == 1) writePartial(buf0, mlA);
    if (quarter == 3) writePartial(buf1, mlB);
    __syncthreads();
    if (quarter == 0) mergeIn(buf0, mlA);
    if (quarter == 2) mergeIn(buf1, mlB);
    __syncthreads();
    if (quarter == 2) writePartial(buf0, mlA);
    __syncthreads();
    if (quarter == 0) {
      mergeIn(buf0, mlA);
      const float inv = 1.0f / l_run;
      float fi[16];
#pragma unroll
      for (int r = 0; r < 16; ++r) fi[r] = __shfl(inv, CRr(r));
#pragma unroll
      for (int db = 0; db < 4; ++db)
#pragma unroll
        for (int r = 0; r < 16; ++r)
          out[((size_t)(tok0 + q0 + CRr(r)) * Hz + h) * 128 + db * 32 + l31] = acc[db][r] * fi[r];
    }
    __syncthreads();               // protect LDS before next pass restages
  }
}

// ---------------------------------------------------------------- launch
extern "C" void kernel_launch(void* const* d_in, const int* in_sizes, int n_in,
                              void* d_out, int out_size, void* d_ws, size_t ws_size,
                              hipStream_t stream) {
  const float* q    = (const float*)d_in[0];
  const float* ckv  = (const float*)d_in[1];
  const float* rope = (const float*)d_in[2];
  const float* wup  = (const float*)d_in[3];
  float* out = (float*)d_out;

  u16* ckvb  = (u16*)d_ws;
  u16* wupb  = ckvb + (size_t)4096 * RANKz;
  u16* kvb   = wupb + (size_t)4096 * RANKz;
  u16* ropeb = kvb + (size_t)4096 * 4096;

  const int nvec = 4096 * RANKz / 4;       // 524288 float4 per matrix
  const int nrope = 4096 * 64 / 4;         // 65536 float4
  cvt_bf16_kernel<<<(2 * nvec + nrope) / 256, 256, 0, stream>>>(ckv, ckvb, wup, wupb, rope, ropeb, nvec, nvec);

  dim3 gg(32, 32);
  gemm_kv_bf16<<<gg, 256, 0, stream>>>(ckvb, wupb, kvb);

  mla_attn_mfma<<<256, 1024, 0, stream>>>(q, kvb, ropeb, out);
}

// Round 7
// 105.296 us; speedup vs baseline: 2.4471x; 2.4471x over previous
//
#include <hip/hip_runtime.h>
#include <stdint.h>

// MLA attention, MI355X round 7.
// Stage 1: kv = compressed_kv @ w_up^T  (bf16 MFMA, m97-style 128x128 tile)
// Stage 2: causal flash attention, 8-wave swapped-QK^T 32x32x16:
//   wave = (k-half 0/1) x (q-strip 0..3); q-tile 128, KV tile 64.
//   LDS 80K/block (Kn dbuf 32K, Kr dbuf 16K, Vt dbuf 32K) -> 2 blocks/CU,
//   4 waves/SIMD, 1 barrier per KV tile. Grid 512 = 1 q-tile/block; pair
//   mapping (bid, bid+256) sums to 18 tiles/CU; XCD-grouped bh for L2 reuse.
// NOTE: __launch_bounds__ 2nd arg = min BLOCKS per CU (CUDA semantics) on this
//       toolchain — (1024,4) in r6 capped VGPR at 64 and spilled catastrophically.

#define Hz 16
#define Sz 1024
#define RANKz 512
#define SCALEf 0.07216878364870323f
#define CRr(r) ((((r) & 3)) + 8 * ((r) >> 2) + 4 * hi)

typedef unsigned short u16;
typedef __attribute__((ext_vector_type(8))) short bf16x8;
typedef __attribute__((ext_vector_type(4))) float f32x4;
typedef __attribute__((ext_vector_type(16))) float f32x16;

__device__ __forceinline__ u16 f2b(float f) {
  union { float f; uint32_t u; } x; x.f = f;
  return (u16)((x.u + 0x7fffu + ((x.u >> 16) & 1u)) >> 16);
}
__device__ __forceinline__ uint32_t cvtpk(float lo, float hi_) {
  uint32_t r;
  asm("v_cvt_pk_bf16_f32 %0, %1, %2" : "=v"(r) : "v"(lo), "v"(hi_));
  return r;
}

// ---------------------------------------------------------------- cvt fp32->bf16
__global__ void cvt_bf16_kernel(const float* __restrict__ a, u16* __restrict__ ao,
                                const float* __restrict__ b, u16* __restrict__ bo,
                                const float* __restrict__ c, u16* __restrict__ co,
                                int na, int nb) {
  int idx = blockIdx.x * blockDim.x + threadIdx.x;
  const float* s; u16* d; int i;
  if (idx < na)            { s = a; d = ao; i = idx; }
  else if (idx < na + nb)  { s = b; d = bo; i = idx - na; }
  else                     { s = c; d = co; i = idx - na - nb; }
  float4 v = ((const float4*)s)[i];
  ushort4 o = make_ushort4(f2b(v.x), f2b(v.y), f2b(v.z), f2b(v.w));
  ((ushort4*)d)[i] = o;
}

// ---------------------------------------------------------------- stage 1 GEMM
__global__ __launch_bounds__(256)
void gemm_kv_bf16(const u16* __restrict__ A,
                  const u16* __restrict__ Bm,
                  u16* __restrict__ C) {
  __shared__ u16 As[128 * 32];
  __shared__ u16 Bs[128 * 32];
  const int tid = threadIdx.x;
  const int w = tid >> 6, lane = tid & 63;
  const int wr = w >> 1, wc = w & 1;
  const int row0 = blockIdx.x * 128, col0 = blockIdx.y * 128;
  f32x4 acc[4][4];
#pragma unroll
  for (int m = 0; m < 4; ++m)
#pragma unroll
    for (int n = 0; n < 4; ++n) acc[m][n] = (f32x4){0.f, 0.f, 0.f, 0.f};

  const int rstage = (lane >> 2);
  const int cstage = (lane & 3) * 8;

  for (int kt = 0; kt < RANKz / 32; ++kt) {
    const int k0 = kt * 32;
#pragma unroll
    for (int i = 0; i < 2; ++i) {
      const int chunk = i * 4 + w;
      const int r = chunk * 16 + rstage;
      const u16* ga = A  + (size_t)(row0 + r) * RANKz + k0 + cstage;
      const u16* gb = Bm + (size_t)(col0 + r) * RANKz + k0 + cstage;
      __builtin_amdgcn_global_load_lds((const __attribute__((address_space(1))) void*)ga,
                                       (__attribute__((address_space(3))) void*)&As[chunk * 512], 16, 0, 0);
      __builtin_amdgcn_global_load_lds((const __attribute__((address_space(1))) void*)gb,
                                       (__attribute__((address_space(3))) void*)&Bs[chunk * 512], 16, 0, 0);
    }
    __syncthreads();
    const int klo = (lane >> 4) * 8;
    bf16x8 af[4], bfr[4];
#pragma unroll
    for (int m = 0; m < 4; ++m)
      af[m] = *(const bf16x8*)&As[(wr * 64 + m * 16 + (lane & 15)) * 32 + klo];
#pragma unroll
    for (int n = 0; n < 4; ++n)
      bfr[n] = *(const bf16x8*)&Bs[(wc * 64 + n * 16 + (lane & 15)) * 32 + klo];
#pragma unroll
    for (int m = 0; m < 4; ++m)
#pragma unroll
      for (int n = 0; n < 4; ++n)
        acc[m][n] = __builtin_amdgcn_mfma_f32_16x16x32_bf16(af[m], bfr[n], acc[m][n], 0, 0, 0);
    __syncthreads();
  }
  const int cb = col0 + wc * 64 + (lane & 15);
  const int rb = row0 + wr * 64 + (lane >> 4) * 4;
#pragma unroll
  for (int m = 0; m < 4; ++m)
#pragma unroll
    for (int n = 0; n < 4; ++n)
#pragma unroll
      for (int j = 0; j < 4; ++j)
        C[(size_t)(rb + m * 16 + j) * 4096 + (cb + n * 16)] = f2b(acc[m][n][j]);
}

// ---------------------------------------------------------------- stage 2: attention
// LDS map (80K/block): Kn dbuf @0 (2x16K), Kr dbuf @32K (2x8K), Vt dbuf @48K (2x16K).
// Merge reuse: mb fp32 @0 (64K), ml @64K (1K).
__global__ __launch_bounds__(512, 2)
void mla_attn_mfma(const float* __restrict__ q,
                   const u16* __restrict__ kvb,     // [T][16][256] bf16
                   const u16* __restrict__ ropeb,   // [T][64] bf16
                   float* __restrict__ out) {       // [T][16][128] fp32
  __shared__ __align__(16) unsigned char LB[81920];

  const int tid = threadIdx.x;
  const int w = tid >> 6, lane = tid & 63;
  const int l31 = lane & 31, hi = lane >> 5;
  const int half = w >> 2, strip = w & 3;

  const int bid = blockIdx.x;
  const int hb = bid >> 6;
  const int qt = (hb < 4) ? (7 - hb) : (hb - 4);   // pairs (c, c+256) sum to 18 tiles
  const int bh = (bid & 7) * 8 + ((bid >> 3) & 7); // 8 bh per XCD
  const int bat = bh >> 4, h = bh & 15;
  const int tok0 = bat * Sz;
  const int q0 = qt * 128 + strip * 32;            // wave strip's q base (in-batch)
  const int ntiles = 2 * qt + 2;

  const int vkp = tid & 31, vdc = tid >> 5;        // V stage: k-pair 0..31, d-chunk8 0..15
  uint4 va, vb;

  auto stageK = [&](int tokt, int buf) {
#pragma unroll
    for (int i = 0; i < 2; ++i) {                  // Kn: 16 chunks of 1KB
      const int c = w * 2 + i;
      const int row = c * 4 + (lane >> 4);
      const int sc = (lane & 15) ^ (row & 7);
      const u16* src = kvb + ((size_t)(tokt + row) * Hz + h) * 256 + sc * 8;
      __builtin_amdgcn_global_load_lds((const __attribute__((address_space(1))) void*)src,
                                       (__attribute__((address_space(3))) void*)(LB + buf * 16384 + c * 1024), 16, 0, 0);
    }
    {                                              // Kr: 8 chunks of 1KB
      const int c = w;
      const int row = c * 8 + (lane >> 3);
      const int sc = (lane & 7) ^ (row & 7);
      const u16* src = ropeb + (size_t)(tokt + row) * 64 + sc * 8;
      __builtin_amdgcn_global_load_lds((const __attribute__((address_space(1))) void*)src,
                                       (__attribute__((address_space(3))) void*)(LB + 32768 + buf * 8192 + c * 1024), 16, 0, 0);
    }
  };
  auto loadV = [&](int tokt) {
    const u16* vp = kvb + ((size_t)(tokt + vkp * 2) * Hz + h) * 256 + 128 + vdc * 8;
    va = *(const uint4*)vp;                        // token 2*vkp,   d vdc*8..+7
    vb = *(const uint4*)(vp + Hz * 256);           // token 2*vkp+1
  };
  auto writeVt = [&](int buf) {
    union { uint4 v; u16 u[8]; } A_, B_;
    A_.v = va; B_.v = vb;
    uint32_t* vt = (uint32_t*)(LB + 49152 + buf * 16384);
#pragma unroll
    for (int i = 0; i < 8; ++i) {
      const int d = vdc * 8 + i;
      vt[d * 32 + 4 * ((vkp >> 2) ^ (d & 7)) + (vkp & 3)] =
          (uint32_t)A_.u[i] | ((uint32_t)B_.u[i] << 16);
    }
  };

  // ---- Q fragments (B-operand), prescaled by SCALE
  bf16x8 qf[12];
  {
    const float* qp = q + ((size_t)(tok0 + q0 + l31) * Hz + h) * 192 + hi * 8;
#pragma unroll
    for (int ds = 0; ds < 12; ++ds) {
      float4 a = *(const float4*)(qp + ds * 16);
      float4 b = *(const float4*)(qp + ds * 16 + 4);
      union { bf16x8 v; u16 u[8]; } t;
      t.u[0] = f2b(a.x * SCALEf); t.u[1] = f2b(a.y * SCALEf);
      t.u[2] = f2b(a.z * SCALEf); t.u[3] = f2b(a.w * SCALEf);
      t.u[4] = f2b(b.x * SCALEf); t.u[5] = f2b(b.y * SCALEf);
      t.u[6] = f2b(b.z * SCALEf); t.u[7] = f2b(b.w * SCALEf);
      qf[ds] = t.v;
    }
  }

  f32x16 acc[4];
#pragma unroll
  for (int db = 0; db < 4; ++db)
#pragma unroll
    for (int r = 0; r < 16; ++r) acc[db][r] = 0.f;
  float m_run = -1e30f, l_run = 0.f;

  // ---- prologue: stage tile 0
  stageK(tok0, 0);
  loadV(tok0);
  __syncthreads();
  writeVt(0);
  __syncthreads();

#pragma unroll 1
  for (int t = 0; t < ntiles; ++t) {
    const int cur = t & 1;
    const bool havenext = (t + 1 < ntiles);
    if (havenext) {
      stageK(tok0 + (t + 1) * 64, cur ^ 1);
      loadV(tok0 + (t + 1) * 64);
    }

    const int kb = t * 64 + half * 32;             // wave's k base this tile
    if (kb <= q0 + 31) {                           // wave-active
      const u16* KnC = (const u16*)(LB + cur * 16384);
      const u16* KrC = (const u16*)(LB + 32768 + cur * 8192);
      const int row_a = half * 32 + l31;
      const int swz = row_a & 7;

      f32x16 s0;
#pragma unroll
      for (int r = 0; r < 16; ++r) s0[r] = 0.f;
      __builtin_amdgcn_s_setprio(1);
#pragma unroll
      for (int ds = 0; ds < 8; ++ds) {
        bf16x8 kf = *(const bf16x8*)&KnC[row_a * 128 + 8 * ((2 * ds + hi) ^ swz)];
        s0 = __builtin_amdgcn_mfma_f32_32x32x16_bf16(kf, qf[ds], s0, 0, 0, 0);
      }
#pragma unroll
      for (int ds = 8; ds < 12; ++ds) {
        bf16x8 kf = *(const bf16x8*)&KrC[row_a * 64 + 8 * ((2 * (ds - 8) + hi) ^ swz)];
        s0 = __builtin_amdgcn_mfma_f32_32x32x16_bf16(kf, qf[ds], s0, 0, 0, 0);
      }
      __builtin_amdgcn_s_setprio(0);

      // ---- causal mask (edge sub-tiles only)
      if (kb + 31 > q0) {
#pragma unroll
        for (int r = 0; r < 16; ++r)
          if (kb + CRr(r) > q0 + l31) s0[r] = -1e30f;
      }

      // ---- in-register online softmax (lane owns q-col l31), defer-max THR=8
      float mx = s0[0];
#pragma unroll
      for (int r = 1; r < 16; ++r) mx = fmaxf(mx, s0[r]);
      mx = fmaxf(mx, __shfl_xor(mx, 32));
      if (__any(mx > m_run + 8.f)) {
        const float nm = fmaxf(m_run, mx);
        const float cr = __expf(m_run - nm);
        m_run = nm; l_run *= cr;
#pragma unroll
        for (int r = 0; r < 16; ++r) {
          const float crg = __shfl(cr, CRr(r));
#pragma unroll
          for (int db = 0; db < 4; ++db) acc[db][r] *= crg;
        }
      }
      float ts = 0.f;
#pragma unroll
      for (int r = 0; r < 16; ++r) { s0[r] = __expf(s0[r] - m_run); ts += s0[r]; }
      ts += __shfl_xor(ts, 32);
      l_run += ts;

      // ---- P -> A-frags: cvt_pk + xor-32 word swap
      bf16x8 pf[2];
#pragma unroll
      for (int ks = 0; ks < 2; ++ks) {
        const int o = ks * 8;
        const uint32_t w0 = cvtpk(s0[o + 0], s0[o + 1]);
        const uint32_t w1 = cvtpk(s0[o + 4], s0[o + 5]);
        const uint32_t w2 = cvtpk(s0[o + 2], s0[o + 3]);
        const uint32_t w3 = cvtpk(s0[o + 6], s0[o + 7]);
        const uint32_t t0 = __shfl_xor(w0, 32), t1 = __shfl_xor(w1, 32);
        const uint32_t t2 = __shfl_xor(w2, 32), t3 = __shfl_xor(w3, 32);
        union { bf16x8 v; uint32_t u[4]; } P;
        P.u[0] = hi ? t1 : w0;
        P.u[1] = hi ? t3 : w2;
        P.u[2] = hi ? w1 : t0;
        P.u[3] = hi ? w3 : t2;
        pf[ks] = P.v;
      }

      // ---- PV: O[32q x 128d] += P[32q x 32k] * V[32k x 128d]
      const u16* VtC = (const u16*)(LB + 49152 + cur * 16384);
      __builtin_amdgcn_s_setprio(1);
#pragma unroll
      for (int ks = 0; ks < 2; ++ks)
#pragma unroll
        for (int db = 0; db < 4; ++db) {
          const int d = db * 32 + l31;
          bf16x8 vf = *(const bf16x8*)&VtC[d * 64 + 8 * ((half * 4 + 2 * ks + hi) ^ (d & 7))];
          acc[db] = __builtin_amdgcn_mfma_f32_32x32x16_bf16(pf[ks], vf, acc[db], 0, 0, 0);
        }
      __builtin_amdgcn_s_setprio(0);
    }

    if (havenext) writeVt(cur ^ 1);   // Vt[cur^1] not read this tile: safe pre-barrier
    __syncthreads();                  // publishes K(t+1)+Vt(t+1); all reads of t done
  }

  // ---- merge the two k-halves (fp32 partials through LDS), write out
  float* mb = (float*)LB;             // 64K (overlays Kn/Kr/Vt0 — reads done)
  float* ml = (float*)(LB + 65536);   // 1K
  if (half == 1) {
#pragma unroll
    for (int db = 0; db < 4; ++db)
#pragma unroll
      for (int g = 0; g < 4; ++g) {
        float4 v = make_float4(acc[db][g * 4 + 0], acc[db][g * 4 + 1],
                               acc[db][g * 4 + 2], acc[db][g * 4 + 3]);
        *(float4*)&mb[strip * 4096 + db * 1024 + g * 256 + lane * 4] = v;
      }
    if (lane < 32) { ml[strip * 64 + lane] = m_run; ml[strip * 64 + 32 + lane] = l_run; }
  }
  __syncthreads();
  if (half == 0) {
    const float mp = ml[strip * 64 + l31];
    const float lp = ml[strip * 64 + 32 + l31];
    const float M  = fmaxf(m_run, mp);
    const float sA = __expf(m_run - M);
    const float sB = __expf(mp - M);
    const float inv = 1.0f / (l_run * sA + lp * sB);
    const float fAl = sA * inv, fBl = sB * inv;
    float fA[16], fB[16];
#pragma unroll
    for (int r = 0; r < 16; ++r) { fA[r] = __shfl(fAl, CRr(r)); fB[r] = __shfl(fBl, CRr(r)); }
#pragma unroll
    for (int db = 0; db < 4; ++db)
#pragma unroll
      for (int g = 0; g < 4; ++g) {
        float4 pv = *(const float4*)&mb[strip * 4096 + db * 1024 + g * 256 + lane * 4];
#pragma unroll
        for (int jj = 0; jj < 4; ++jj) {
          const int r = g * 4 + jj;
          const float pvj = (jj == 0) ? pv.x : (jj == 1) ? pv.y : (jj == 2) ? pv.z : pv.w;
          out[((size_t)(tok0 + q0 + CRr(r)) * Hz + h) * 128 + db * 32 + l31] =
              acc[db][r] * fA[r] + pvj * fB[r];
        }
      }
  }
}

// ---------------------------------------------------------------- launch
extern "C" void kernel_launch(void* const* d_in, const int* in_sizes, int n_in,
                              void* d_out, int out_size, void* d_ws, size_t ws_size,
                              hipStream_t stream) {
  const float* q    = (const float*)d_in[0];
  const float* ckv  = (const float*)d_in[1];
  const float* rope = (const float*)d_in[2];
  const float* wup  = (const float*)d_in[3];
  float* out = (float*)d_out;

  u16* ckvb  = (u16*)d_ws;
  u16* wupb  = ckvb + (size_t)4096 * RANKz;
  u16* kvb   = wupb + (size_t)4096 * RANKz;
  u16* ropeb = kvb + (size_t)4096 * 4096;

  const int nvec = 4096 * RANKz / 4;       // 524288 float4 per matrix
  const int nrope = 4096 * 64 / 4;         // 65536 float4
  cvt_bf16_kernel<<<(2 * nvec + nrope) / 256, 256, 0, stream>>>(ckv, ckvb, wup, wupb, rope, ropeb, nvec, nvec);

  dim3 gg(32, 32);
  gemm_kv_bf16<<<gg, 256, 0, stream>>>(ckvb, wupb, kvb);

  mla_attn_mfma<<<512, 512, 0, stream>>>(q, kvb, ropeb, out);
}